// Round 5
// baseline (1834.310 us; speedup 1.0000x reference)
//
#include <hip/hip_runtime.h>
#include <hip/hip_fp16.h>
#include <cstdint>

#define LATN 16
#define LONGN 12
#define PP 192          // LAT*LONG positions per n
#define CIN 128
#define CMID 128
#define EPSV 1e-5f
#define SPLIT 8         // blocks per n (channel split)
#define CHB 16          // channels per block (= 2 GroupNorm groups)
#define CST 196         // [c][p] tile stride (floats), 16B-aligned rows
#define GN 16           // n's per block
#define UMAX 4          // staged gather passes

typedef float v2f __attribute__((ext_vector_type(2)));

// ---------------- counting sort of scatter records by destination n ----------------

__global__ void count_kernel(const int* __restrict__ pidx, int* __restrict__ counts, int E) {
    int e = blockIdx.x * 256 + threadIdx.x;
    if (e >= E) return;
#pragma unroll
    for (int i = 0; i < 4; i++) {
        int v = pidx[i * E + e];
        int n = v / PP;
        atomicAdd(&counts[n], 1);
    }
}

// single block, 1024 threads, N <= 4096. counts may alias cur.
__global__ void scan_kernel(const int* __restrict__ counts, int* __restrict__ start,
                            int* __restrict__ cur, int N) {
    __shared__ int sdata[1024];
    int tid = threadIdx.x;
    int c[4];
    int s = 0;
#pragma unroll
    for (int j = 0; j < 4; j++) {
        int idx = tid * 4 + j;
        c[j] = (idx < N) ? counts[idx] : 0;
        s += c[j];
    }
    sdata[tid] = s;
    __syncthreads();
    for (int off = 1; off < 1024; off <<= 1) {
        int t = (tid >= off) ? sdata[tid - off] : 0;
        __syncthreads();
        sdata[tid] += t;
        __syncthreads();
    }
    int excl = sdata[tid] - s;
#pragma unroll
    for (int j = 0; j < 4; j++) {
        int idx = tid * 4 + j;
        if (idx < N) { start[idx] = excl; cur[idx] = excl; }
        excl += c[j];
    }
    if (tid == 1023) start[N] = sdata[1023];
}

// emit bucketed records: rec.x = src | (p<<18), rec.y = delta bits
__global__ void record_kernel(const int* __restrict__ pidx, const int* __restrict__ src_idx,
                              const float* __restrict__ delta, int* __restrict__ cur,
                              uint2* __restrict__ rec, int E) {
    int e = blockIdx.x * 256 + threadIdx.x;
    if (e >= E) return;
    int src = src_idx[e];
#pragma unroll
    for (int i = 0; i < 4; i++) {
        int v = pidx[i * E + e];
        int n = v / PP;
        int p = v - n * PP;
        int pos = atomicAdd(&cur[n], 1);
        rec[pos] = make_uint2((uint32_t)src | ((uint32_t)p << 18),
                              __float_as_uint(delta[i * E + e]));
    }
}

// weights -> f16x2 k-pairs, layout [i_pg][kp][o] (lane-coalesced over o)
__global__ void wt2_kernel(const float* __restrict__ w, uint32_t* __restrict__ wt2) {
    int id = blockIdx.x * 256 + threadIdx.x;
    if (id >= CIN * 6 * CMID) return;
    int o = id & 127;
    int kp = (id >> 7) % 6;
    int i = id / (128 * 6);
    float a = w[(o * 128 + i) * 12 + 2 * kp];
    float b = w[(o * 128 + i) * 12 + 2 * kp + 1];
    __half2 h = __floats2half2_rn(a, b);
    wt2[id] = *reinterpret_cast<uint32_t*>(&h);
}

// ---------------- fused: weight-resident, double-buffered tiles, G n's per block ----

#define CONV_L(l) { \
    const float4 ra = *(const float4*)(tc + (lh * 8 + (l)) * LONGN); \
    const float4 rb = *(const float4*)(tc + (lh * 8 + (l)) * LONGN + 4); \
    const float4 rcc = *(const float4*)(tc + (lh * 8 + (l)) * LONGN + 8); \
    float rr[12] = {ra.x, ra.y, ra.z, ra.w, rb.x, rb.y, rb.z, rb.w, rcc.x, rcc.y, rcc.z, rcc.w}; \
    v2f rp[12]; \
    _Pragma("unroll") \
    for (int jj = 0; jj < 12; jj++) { rp[jj].x = rr[jj]; rp[jj].y = rr[(jj + 1) % 12]; } \
    _Pragma("unroll") \
    for (int kp = 0; kp < 6; kp++) { \
        uint32_t wp = wreg[(l)][kp]; \
        __half2 h2 = *reinterpret_cast<__half2*>(&wp); \
        float wlo = __half2float(h2.x); \
        float whi = __half2float(h2.y); \
        v2f wl2 = {wlo, wlo}, wh2 = {whi, whi}; \
        _Pragma("unroll") \
        for (int u = 0; u < 6; u++) { \
            acc2[u] += wl2 * rp[(2 * kp + 2 * u + 6) % 12]; \
            acc2[u] += wh2 * rp[(2 * kp + 2 * u + 7) % 12]; \
        } \
    } }

__global__ __launch_bounds__(256, 4) void fused_kernel(
    const float* __restrict__ x, const uint2* __restrict__ rec,
    const int* __restrict__ start, const uint32_t* __restrict__ wt2,
    const float* __restrict__ conv_b, const float* __restrict__ gn_w,
    const float* __restrict__ gn_b, float* __restrict__ out) {

    __shared__ __align__(16) float lds[2 * CHB * CST + 16 * CHB * LONGN + CHB * LONGN];
    float* tileA = lds;                          // [c][p] stride CST
    float* tileB = lds + CHB * CST;
    float* pbuf  = lds + 2 * CHB * CST;          // [s16][o][t]
    float* zbuf  = pbuf + 16 * CHB * LONGN;      // [o][t]

    const int bid = blockIdx.x;
    const int nbase = (bid >> 3) * GN;
    const int b = bid & 7;
    const int tid = threadIdx.x;

    const int o_local = tid & 15;
    const int s16 = tid >> 4;               // 0..15 (combines lh, q)
    const int lh = s16 & 1;                 // lat half
    const int q = tid >> 5;                 // 0..7 in-channel-within-group
    const int o = b * CHB + o_local;        // global out channel
    const int c_local = (o_local & 8) + q;  // tile channel

    // ---- resident f16x2 weights: 48 VGPRs ----
    uint32_t wreg[8][6];
#pragma unroll
    for (int l = 0; l < 8; l++) {
        int i_pg = q * LATN + lh * 8 + l;
#pragma unroll
        for (int kp = 0; kp < 6; kp++)
            wreg[l][kp] = wt2[(i_pg * 6 + kp) * CMID + o];
    }

    const int j4 = tid & 3;                 // lane-within-record (4 ch each)
    const int slot = tid >> 2;              // 0..63 records in flight
    const float* xrow = x + b * CHB + j4 * 4;

    // ---- prologue: zero + scatter n0 into tileA ----
    {
        float4 zz = {0.f, 0.f, 0.f, 0.f};
        float4* t4 = (float4*)tileA;
#pragma unroll
        for (int r = 0; r < 4; r++) {
            int idx = tid + r * 256;
            if (idx < CHB * CST / 4) t4[idx] = zz;
        }
    }
    __syncthreads();
    {
        int g0 = start[nbase], g1 = start[nbase + 1];
        for (int it = g0 + slot; it < g1; it += 64) {
            uint2 r2 = rec[it];
            float dl = __uint_as_float(r2.y);
            int src = (int)(r2.x & 0x3FFFFu);
            int p = (int)(r2.x >> 18);
            float4 xq = *(const float4*)(xrow + (size_t)src * CIN);
            float* tp = tileA + p;
#pragma unroll
            for (int m = 0; m < 4; m++)
                atomicAdd(tp + (j4 * 4 + m) * CST, ((const float*)&xq)[m] * dl);
        }
    }
    __syncthreads();

    // ---- main loop over G n's ----
    for (int i = 0; i < GN; i++) {
        const int n_i = nbase + i;
        float* tcur = (i & 1) ? tileB : tileA;
        float* tnxt = (i & 1) ? tileA : tileB;
        const bool more = (i + 1 < GN);

        // zero next tile (phase A)
        if (more) {
            float4 zz = {0.f, 0.f, 0.f, 0.f};
            float4* t4 = (float4*)tnxt;
#pragma unroll
            for (int r = 0; r < 4; r++) {
                int idx = tid + r * 256;
                if (idx < CHB * CST / 4) t4[idx] = zz;
            }
        }

        // gather issue: rec loads for n_{i+1}
        uint2 rv[UMAX];
        int gbase = 0, g1 = 0, cnt = 0;
        if (more) {
            gbase = start[n_i + 1] + slot;
            g1 = start[n_i + 2];
#pragma unroll
            for (int u = 0; u < UMAX; u++) {
                if (gbase + u * 64 < g1) { rv[u] = rec[gbase + u * 64]; cnt = u + 1; }
            }
        }

        // conv from tile[cur], weights from registers
        v2f acc2[6];
#pragma unroll
        for (int u = 0; u < 6; u++) acc2[u] = (v2f)(0.f);
        const float* tc = tcur + c_local * CST;

#pragma unroll
        for (int l = 0; l < 2; l++) CONV_L(l)

        // x loads for n_{i+1} (hide under remaining conv)
        float4 xv[UMAX];
#pragma unroll
        for (int u = 0; u < UMAX; u++) {
            if (u < cnt) {
                int src = (int)(rv[u].x & 0x3FFFFu);
                xv[u] = *(const float4*)(xrow + (size_t)src * CIN);
            }
        }

#pragma unroll
        for (int l = 2; l < 8; l++) CONV_L(l)

        __syncthreads();   // bar1: zero(tnxt) complete

        // scatter n_{i+1} into tnxt (phase B)
        if (more) {
#pragma unroll
            for (int u = 0; u < UMAX; u++) {
                if (u < cnt) {
                    float dl = __uint_as_float(rv[u].y);
                    int p = (int)(rv[u].x >> 18);
                    float* tp = tnxt + p;
#pragma unroll
                    for (int m = 0; m < 4; m++)
                        atomicAdd(tp + (j4 * 4 + m) * CST, ((const float*)&xv[u])[m] * dl);
                }
            }
            for (int it = gbase + UMAX * 64; it < g1; it += 64) {   // rare overflow
                uint2 r2 = rec[it];
                float dl = __uint_as_float(r2.y);
                int src = (int)(r2.x & 0x3FFFFu);
                int p = (int)(r2.x >> 18);
                float4 xq = *(const float4*)(xrow + (size_t)src * CIN);
                float* tp = tnxt + p;
#pragma unroll
                for (int m = 0; m < 4; m++)
                    atomicAdd(tp + (j4 * 4 + m) * CST, ((const float*)&xq)[m] * dl);
            }
        }

        // pbuf partial write
        {
            float* pw = pbuf + s16 * (CHB * LONGN) + o_local * LONGN;
            *(float4*)(pw + 0) = float4{acc2[0].x, acc2[0].y, acc2[1].x, acc2[1].y};
            *(float4*)(pw + 4) = float4{acc2[2].x, acc2[2].y, acc2[3].x, acc2[3].y};
            *(float4*)(pw + 8) = float4{acc2[4].x, acc2[4].y, acc2[5].x, acc2[5].y};
        }
        __syncthreads();   // bar2

        // stage1: z-sum + silu (192 threads, coalesced LDS)
        if (tid < CHB * LONGN) {
            float z = conv_b[b * CHB + tid / LONGN];
#pragma unroll
            for (int s = 0; s < 16; s++) z += pbuf[s * (CHB * LONGN) + tid];
            zbuf[tid] = z / (1.f + __expf(-z));
        }
        __syncthreads();   // bar3

        // stage2: pool + groupnorm + out (16 threads, shfl over 8-lane groups)
        if (tid < CHB) {
            const float* zr = zbuf + tid * LONGN;
            float4 za = *(const float4*)(zr);
            float4 zb = *(const float4*)(zr + 4);
            float4 zc = *(const float4*)(zr + 8);
            float sv = (za.x + za.y + za.z + za.w + zb.x + zb.y + zb.z + zb.w +
                        zc.x + zc.y + zc.z + zc.w) * (1.f / 12.f);
            float s1 = sv, s2 = sv * sv;
#pragma unroll
            for (int m = 1; m < 8; m <<= 1) {
                s1 += __shfl_xor(s1, m);
                s2 += __shfl_xor(s2, m);
            }
            float mu = s1 * 0.125f;
            float var = fmaxf(s2 * 0.125f - mu * mu, 0.f);
            float inv = rsqrtf(var + EPSV);
            int oc = b * CHB + tid;
            out[(size_t)n_i * CMID + oc] = (sv - mu) * inv * gn_w[oc] + gn_b[oc];
        }
    }
}

extern "C" void kernel_launch(void* const* d_in, const int* in_sizes, int n_in,
                              void* d_out, int out_size, void* d_ws, size_t ws_size,
                              hipStream_t stream) {
    const float* x = (const float*)d_in[0];
    const int* pidx = (const int*)d_in[2];
    const float* delta = (const float*)d_in[3];
    const int* src_idx = (const int*)d_in[4];
    const float* conv_w = (const float*)d_in[5];
    const float* conv_b = (const float*)d_in[6];
    const float* gn_w = (const float*)d_in[7];
    const float* gn_b = (const float*)d_in[8];
    float* out = (float*)d_out;

    int E = in_sizes[0] / CIN;          // 200000
    int N = out_size / CMID;            // 4096

    char* ws = (char*)d_ws;
    size_t off = 0;
    auto alloc = [&](size_t bytes) {
        size_t cur = off;
        off = (off + bytes + 255) & ~(size_t)255;
        return cur;
    };
    int* cur = (int*)(ws + alloc((size_t)N * 4));
    int* start = (int*)(ws + alloc((size_t)(N + 1) * 4));
    uint2* rec = (uint2*)(ws + alloc((size_t)4 * E * 8));
    uint32_t* wt2 = (uint32_t*)(ws + alloc((size_t)CIN * 6 * CMID * 4));

    hipMemsetAsync(cur, 0, (size_t)N * 4, stream);

    int gE = (E + 255) / 256;
    count_kernel<<<gE, 256, 0, stream>>>(pidx, cur, E);
    scan_kernel<<<1, 1024, 0, stream>>>(cur, start, cur, N);
    record_kernel<<<gE, 256, 0, stream>>>(pidx, src_idx, delta, cur, rec, E);
    wt2_kernel<<<(CIN * 6 * CMID + 255) / 256, 256, 0, stream>>>(conv_w, wt2);
    fused_kernel<<<(N / GN) * SPLIT, 256, 0, stream>>>(x, rec, start, wt2, conv_b, gn_w, gn_b, out);
}

// Round 6
// 732.030 us; speedup vs baseline: 2.5058x; 2.5058x over previous
//
#include <hip/hip_runtime.h>
#include <hip/hip_fp16.h>
#include <cstdint>

#define LATN 16
#define LONGN 12
#define PP 192          // LAT*LONG positions per n
#define CIN 128
#define CMID 128
#define EPSV 1e-5f
#define SPLIT 4         // blocks per n (channel split)
#define CHB 32          // channels per block
#define CST 196         // [row][p] tile stride (floats), 16B-aligned rows

typedef float v2f __attribute__((ext_vector_type(2)));

// ---------------- counting sort of scatter records by destination n ----------------

__global__ void count_kernel(const int* __restrict__ pidx, int* __restrict__ counts, int E) {
    int e = blockIdx.x * 256 + threadIdx.x;
    if (e >= E) return;
#pragma unroll
    for (int i = 0; i < 4; i++) {
        int v = pidx[i * E + e];
        int n = v / PP;
        atomicAdd(&counts[n], 1);
    }
}

// single block, 1024 threads, N <= 4096. counts may alias cur.
__global__ void scan_kernel(const int* __restrict__ counts, int* __restrict__ start,
                            int* __restrict__ cur, int N) {
    __shared__ int sdata[1024];
    int tid = threadIdx.x;
    int c[4];
    int s = 0;
#pragma unroll
    for (int j = 0; j < 4; j++) {
        int idx = tid * 4 + j;
        c[j] = (idx < N) ? counts[idx] : 0;
        s += c[j];
    }
    sdata[tid] = s;
    __syncthreads();
    for (int off = 1; off < 1024; off <<= 1) {
        int t = (tid >= off) ? sdata[tid - off] : 0;
        __syncthreads();
        sdata[tid] += t;
        __syncthreads();
    }
    int excl = sdata[tid] - s;
#pragma unroll
    for (int j = 0; j < 4; j++) {
        int idx = tid * 4 + j;
        if (idx < N) { start[idx] = excl; cur[idx] = excl; }
        excl += c[j];
    }
    if (tid == 1023) start[N] = sdata[1023];
}

// emit bucketed records: rec.x = src | (p<<18), rec.y = delta bits
__global__ void record_kernel(const int* __restrict__ pidx, const int* __restrict__ src_idx,
                              const float* __restrict__ delta, int* __restrict__ cur,
                              uint2* __restrict__ rec, int E) {
    int e = blockIdx.x * 256 + threadIdx.x;
    if (e >= E) return;
    int src = src_idx[e];
#pragma unroll
    for (int i = 0; i < 4; i++) {
        int v = pidx[i * E + e];
        int n = v / PP;
        int p = v - n * PP;
        int pos = atomicAdd(&cur[n], 1);
        rec[pos] = make_uint2((uint32_t)src | ((uint32_t)p << 18),
                              __float_as_uint(delta[i * E + e]));
    }
}

// weights -> f16x2 k-pairs, layout [i_pg][kp][o] (lane-coalesced over o)
__global__ void wt2_kernel(const float* __restrict__ w, uint32_t* __restrict__ wt2) {
    int id = blockIdx.x * 256 + threadIdx.x;
    if (id >= CIN * 6 * CMID) return;
    int o = id & 127;
    int kp = (id >> 7) % 6;
    int i = id / (128 * 6);
    float a = w[(o * 128 + i) * 12 + 2 * kp];
    float b = w[(o * 128 + i) * 12 + 2 * kp + 1];
    __half2 h = __floats2half2_rn(a, b);
    wt2[id] = *reinterpret_cast<uint32_t*>(&h);
}

// ---------------- fused: scatter->LDS tile, conv, silu, pool, groupnorm ----------------
// One block handles 32 channels (= 4 GroupNorm groups) of one n.
// Tile layout: [row][p], row(c) = (c&7)*4 + (c>>3)  (bank-spread permutation)

__global__ __launch_bounds__(256, 6) void fused_kernel(
    const float* __restrict__ x, const uint2* __restrict__ rec,
    const int* __restrict__ start, const uint32_t* __restrict__ wt2,
    const float* __restrict__ conv_b, const float* __restrict__ gn_w,
    const float* __restrict__ gn_b, float* __restrict__ out) {
    __shared__ __align__(16) float tile[CHB * CST];     // 25088 B

    int bid = blockIdx.x;
    int n = bid >> 2;
    int b = bid & 3;
    int tid = threadIdx.x;

    // zero tile
    {
        float4 zz = {0.f, 0.f, 0.f, 0.f};
        float4* t4 = (float4*)tile;
#pragma unroll
        for (int r = 0; r < 7; r++) {
            int idx = tid + r * 256;
            if (idx < CHB * CST / 4) t4[idx] = zz;
        }
    }
    __syncthreads();

    // ---- scatter: 8 lanes/record (float4), 4-deep software pipeline ----
    int b0 = start[n], b1 = start[n + 1];
    {
        int il = tid & 7;                   // lane within record: 4 channels each
        int slot = tid >> 3;                // 0..31
        int cbase = b * CHB + il * 4;       // global channel of this lane's float4
        // rows for this lane's 4 channels (c_local = il*4+m)
        int row0 = ((il * 4 + 0) & 7) * 4 + ((il * 4 + 0) >> 3);
        int row1 = ((il * 4 + 1) & 7) * 4 + ((il * 4 + 1) >> 3);
        int row2 = ((il * 4 + 2) & 7) * 4 + ((il * 4 + 2) >> 3);
        int row3 = ((il * 4 + 3) & 7) * 4 + ((il * 4 + 3) >> 3);
        for (int it = b0 + slot; it < b1; it += 32 * 4) {
            uint2 rv[4];
            float4 xv[4];
            int idx[4];
#pragma unroll
            for (int u = 0; u < 4; u++) {
                idx[u] = it + u * 32;
                if (idx[u] < b1) rv[u] = rec[idx[u]];
            }
#pragma unroll
            for (int u = 0; u < 4; u++) {
                if (idx[u] < b1) {
                    int src = (int)(rv[u].x & 0x3FFFFu);
                    xv[u] = *(const float4*)(x + (size_t)src * CIN + cbase);
                }
            }
#pragma unroll
            for (int u = 0; u < 4; u++) {
                if (idx[u] < b1) {
                    float dl = __uint_as_float(rv[u].y);
                    int p = (int)(rv[u].x >> 18);
                    atomicAdd(&tile[row0 * CST + p], xv[u].x * dl);
                    atomicAdd(&tile[row1 * CST + p], xv[u].y * dl);
                    atomicAdd(&tile[row2 * CST + p], xv[u].z * dl);
                    atomicAdd(&tile[row3 * CST + p], xv[u].w * dl);
                }
            }
        }
    }
    __syncthreads();

    // ---- grouped circular conv: thread = (q = tid>>5, o_local = tid&31) ----
    int o_local = tid & 31;
    int q = tid >> 5;                       // 0..7 = in-channel-within-group
    int g_local = o_local >> 3;             // 0..3
    int o = b * CHB + o_local;              // global out channel
    int row = q * 4 + g_local;              // permuted tile row for channel g*8+q

    v2f acc2[6];
#pragma unroll
    for (int u = 0; u < 6; u++) acc2[u] = (v2f)(0.f);

    const float* tc = tile + row * CST;
    const uint32_t* wcol = wt2 + (size_t)(q * LATN) * 6 * CMID + o;

#pragma unroll
    for (int lat = 0; lat < LATN; lat++) {
        const float4 ra = *(const float4*)(tc + lat * LONGN);
        const float4 rb = *(const float4*)(tc + lat * LONGN + 4);
        const float4 rc = *(const float4*)(tc + lat * LONGN + 8);
        float r[12] = {ra.x, ra.y, ra.z, ra.w, rb.x, rb.y, rb.z, rb.w,
                       rc.x, rc.y, rc.z, rc.w};
        v2f rp[12];
#pragma unroll
        for (int j = 0; j < 12; j++) {
            rp[j].x = r[(j + 6) % 12];
            rp[j].y = r[(j + 7) % 12];
        }
        const uint32_t* wrow = wcol + (size_t)(lat * 6) * CMID;
#pragma unroll
        for (int kp = 0; kp < 6; kp++) {
            uint32_t wp = wrow[kp * CMID];
            __half2 h2 = *reinterpret_cast<__half2*>(&wp);
            float wlo = __half2float(h2.x);
            float whi = __half2float(h2.y);
            v2f wl2 = {wlo, wlo}, wh2 = {whi, whi};
#pragma unroll
            for (int u = 0; u < 6; u++) {
                acc2[u] += wl2 * rp[(2 * kp + 2 * u) % 12];
                acc2[u] += wh2 * rp[(2 * kp + 2 * u + 1) % 12];
            }
        }
    }
    __syncthreads();

    // ---- reduce partials across q (LDS), silu, pool, groupnorm ----
    float* pbuf = tile;                     // 8*12*32 = 3072 floats
#pragma unroll
    for (int u = 0; u < 6; u++) {
        pbuf[(q * 12 + 2 * u) * 32 + o_local] = acc2[u].x;
        pbuf[(q * 12 + 2 * u + 1) * 32 + o_local] = acc2[u].y;
    }
    __syncthreads();

    float* gbuf = tile + 8 * 12 * 32;       // 32 floats
    float sv = 0.f;
    if (tid < 32) {
        float bias = conv_b[b * CHB + tid];
#pragma unroll
        for (int t = 0; t < 12; t++) {
            float z = bias;
#pragma unroll
            for (int qq = 0; qq < 8; qq++) z += pbuf[(qq * 12 + t) * 32 + tid];
            sv += z / (1.f + __expf(-z));
        }
        sv *= (1.f / 12.f);
        gbuf[tid] = sv;
    }
    __syncthreads();
    if (tid < 32) {
        int gb = tid & ~7;
        float mu = 0.f, m2 = 0.f;
#pragma unroll
        for (int j = 0; j < 8; j++) {
            float v = gbuf[gb + j];
            mu += v;
            m2 += v * v;
        }
        mu *= 0.125f;
        float var = m2 * 0.125f - mu * mu;
        var = fmaxf(var, 0.f);
        float inv = rsqrtf(var + EPSV);
        int oc = b * CHB + tid;
        out[(size_t)n * CMID + oc] = (sv - mu) * inv * gn_w[oc] + gn_b[oc];
    }
}

extern "C" void kernel_launch(void* const* d_in, const int* in_sizes, int n_in,
                              void* d_out, int out_size, void* d_ws, size_t ws_size,
                              hipStream_t stream) {
    const float* x = (const float*)d_in[0];
    const int* pidx = (const int*)d_in[2];
    const float* delta = (const float*)d_in[3];
    const int* src_idx = (const int*)d_in[4];
    const float* conv_w = (const float*)d_in[5];
    const float* conv_b = (const float*)d_in[6];
    const float* gn_w = (const float*)d_in[7];
    const float* gn_b = (const float*)d_in[8];
    float* out = (float*)d_out;

    int E = in_sizes[0] / CIN;          // 200000
    int N = out_size / CMID;            // 4096

    char* ws = (char*)d_ws;
    size_t off = 0;
    auto alloc = [&](size_t bytes) {
        size_t cur = off;
        off = (off + bytes + 255) & ~(size_t)255;
        return cur;
    };
    int* cur = (int*)(ws + alloc((size_t)N * 4));
    int* start = (int*)(ws + alloc((size_t)(N + 1) * 4));
    uint2* rec = (uint2*)(ws + alloc((size_t)4 * E * 8));
    uint32_t* wt2 = (uint32_t*)(ws + alloc((size_t)CIN * 6 * CMID * 4));

    hipMemsetAsync(cur, 0, (size_t)N * 4, stream);

    int gE = (E + 255) / 256;
    count_kernel<<<gE, 256, 0, stream>>>(pidx, cur, E);
    scan_kernel<<<1, 1024, 0, stream>>>(cur, start, cur, N);
    record_kernel<<<gE, 256, 0, stream>>>(pidx, src_idx, delta, cur, rec, E);
    wt2_kernel<<<(CIN * 6 * CMID + 255) / 256, 256, 0, stream>>>(conv_w, wt2);
    fused_kernel<<<N * SPLIT, 256, 0, stream>>>(x, rec, start, wt2, conv_b, gn_w, gn_b, out);
}